// Round 17
// baseline (133.839 us; speedup 1.0000x reference)
//
#include <hip/hip_runtime.h>
#include <math.h>
#include <stdint.h>

#define BB 2
#define SS 2048
#define EE 1024
#define HH 16
#define DD 64
#define E3 3072
#define NR (BB*SS)   // 4096 rows
#define QKW 2048     // Q+K packed row width
#define NSPLIT 2     // attention K-split (R12-proven; 3 and 4 both regressed)
#define QB 128       // attention q-block rows (R16-proven: 4 blocks/CU, 60 VGPR)

// exp(s/8) = exp2(s * 0.18033688)
#define C2Q 0.18033688011112042f

typedef __attribute__((ext_vector_type(8))) short short8;   // 8 bf16
typedef __attribute__((ext_vector_type(4))) float f32x4;    // 4 fp32
typedef __attribute__((ext_vector_type(4))) uint uint4v;

__device__ __forceinline__ ushort f2bf(float f) {
    uint u = __float_as_uint(f);
    uint r = u + 0x7FFFu + ((u >> 16) & 1u);   // RNE
    return (ushort)(r >> 16);
}
__device__ __forceinline__ short8 pack8(float4 a, float4 b) {
    short8 v;
    v[0] = (short)f2bf(a.x); v[1] = (short)f2bf(a.y); v[2] = (short)f2bf(a.z); v[3] = (short)f2bf(a.w);
    v[4] = (short)f2bf(b.x); v[5] = (short)f2bf(b.y); v[6] = (short)f2bf(b.z); v[7] = (short)f2bf(b.w);
    return v;
}
__device__ __forceinline__ uint cvtpk(float lo, float hi) {
    uint d;
    asm("v_cvt_pk_bf16_f32 %0, %1, %2" : "=v"(d) : "v"(lo), "v"(hi));
    return d;
}
__device__ __forceinline__ float vexp2(float x) {
    float r;
    asm("v_exp_f32 %0, %1" : "=v"(r) : "v"(x));
    return r;
}
__device__ __forceinline__ float bf2f(short s) {
    return __uint_as_float(((uint)(ushort)s) << 16);
}

// ---------------- fp32->bf16 conversion + last-break scan, one launch ----------------
// Blocks [0, NCVT): convert x/win/wout. Blocks [NCVT, NCVT+BB): scan tokens.
__global__ __launch_bounds__(256) void cvt_scan(const float* __restrict__ x,
                                                const float* __restrict__ win,
                                                const float* __restrict__ wout,
                                                ushort* __restrict__ xb,
                                                ushort* __restrict__ winb,
                                                ushort* __restrict__ woutb,
                                                const int* __restrict__ tok,
                                                int* __restrict__ lbrk) {
    const int NX = NR * EE / 8, NW = E3 * EE / 8, NWO = EE * EE / 8;
    const int NCVT = (NX + NW + NWO) / 256;
    __shared__ int pmax[256];
    int blk = blockIdx.x;
    int t = threadIdx.x;
    if (blk >= NCVT) {
        int b = blk - NCVT;
        int loc[8];
        int base = b * SS + t * 8;
        int lm = -1;
#pragma unroll
        for (int i = 0; i < 8; i++) {
            if (tok[base + i] == 13) lm = t * 8 + i;
            loc[i] = lm;
        }
        pmax[t] = lm;
        __syncthreads();
        if (t == 0) {
            int acc = -1;
            for (int i = 0; i < 256; i++) { int tmp = pmax[i]; pmax[i] = acc; acc = max(acc, tmp); }
        }
        __syncthreads();
        int off = pmax[t];
#pragma unroll
        for (int i = 0; i < 8; i++)
            lbrk[base + i] = max(off, loc[i]);
        return;
    }
    int i = blk * 256 + t;
    const float* src; ushort* dst; int j;
    if (i < NX)           { src = x;    dst = xb;    j = i; }
    else if (i < NX + NW) { src = win;  dst = winb;  j = i - NX; }
    else                  { src = wout; dst = woutb; j = i - NX - NW; }
    const float4* p = (const float4*)src + (size_t)j * 2;
    float4 a = p[0], b = p[1];
    *((short8*)dst + j) = pack8(a, b);
}

// ---------------- bf16 MFMA GEMM (R14-proven, unchanged; used for QKV only) ----------------
template<int OUT_BF16>
__global__ __launch_bounds__(256) void gemm_mfma(const ushort* __restrict__ A,
                                                 const ushort* __restrict__ Bw,
                                                 const float* __restrict__ bias,
                                                 void* __restrict__ Cv,
                                                 ushort* __restrict__ vTp,
                                                 int strideC, int K) {
    __shared__ ushort As[2][128 * 32];
    __shared__ ushort Bs[2][128 * 32];
    int id = blockIdx.y * gridDim.x + blockIdx.x;
    {
        int cpx = (gridDim.x * gridDim.y) >> 3;
        id = (id & 7) * cpx + (id >> 3);
    }
    const int bm = (id % gridDim.x) * 128;
    const int bn = (id / gridDim.x) * 128;
    const int tid = threadIdx.x;
    const int w = tid >> 6, lane = tid & 63;
    const int l16 = lane & 15, lk = lane >> 4;
    const int wr = w >> 1, wc = w & 1;

    f32x4 acc[4][4];
#pragma unroll
    for (int mi = 0; mi < 4; mi++)
#pragma unroll
        for (int ni = 0; ni < 4; ni++)
            acc[mi][ni] = (f32x4){0.f, 0.f, 0.f, 0.f};

    const int ci  = w * 2;
    const int rA0 = lane >> 2;
    const int gsh = (lane & 3) ^ ((lane >> 2) & 3);

#define GSTAGE(buf, k0)                                                                      \
    {                                                                                        \
        _Pragma("unroll") for (int i2 = 0; i2 < 2; ++i2) {                                   \
            int c = ci + i2;                                                                 \
            int r = c * 16 + rA0;                                                            \
            const ushort* ga = A + (size_t)(bn + r) * K + (k0) + gsh * 8;                    \
            const ushort* gb = Bw + (size_t)(bm + r) * K + (k0) + gsh * 8;                   \
            __builtin_amdgcn_global_load_lds(                                                \
                (const __attribute__((address_space(1))) void*)ga,                           \
                (__attribute__((address_space(3))) void*)((char*)&As[buf][0] + c * 1024),    \
                16, 0, 0);                                                                   \
            __builtin_amdgcn_global_load_lds(                                                \
                (const __attribute__((address_space(1))) void*)gb,                           \
                (__attribute__((address_space(3))) void*)((char*)&Bs[buf][0] + c * 1024),    \
                16, 0, 0);                                                                   \
        }                                                                                    \
    }

    const int pp = (lk ^ (l16 & 3)) * 8;
    const int NT = K / 32;

    GSTAGE(0, 0);
    __syncthreads();

    for (int t = 0; t < NT; ++t) {
        int cur = t & 1;
        if (t + 1 < NT) GSTAGE(cur ^ 1, (t + 1) * 32);
        const ushort* Ab = &As[cur][0];
        const ushort* Bb = &Bs[cur][0];
        short8 af[4], bfr[4];
#pragma unroll
        for (int mi = 0; mi < 4; ++mi) {
            int r = wr * 64 + mi * 16 + l16;
            af[mi] = *(const short8*)(Ab + r * 32 + pp);
        }
#pragma unroll
        for (int ni = 0; ni < 4; ++ni) {
            int r = wc * 64 + ni * 16 + l16;
            bfr[ni] = *(const short8*)(Bb + r * 32 + pp);
        }
#pragma unroll
        for (int mi = 0; mi < 4; ++mi)
#pragma unroll
            for (int ni = 0; ni < 4; ++ni)
                acc[mi][ni] = __builtin_amdgcn_mfma_f32_16x16x32_bf16(af[mi], bfr[ni], acc[mi][ni], 0, 0, 0);
        __syncthreads();
    }
#undef GSTAGE

#pragma unroll
    for (int ni = 0; ni < 4; ++ni) {
        int col = bm + wc * 64 + ni * 16 + l16;
        float bv = bias[col];
        const bool isV = OUT_BF16 && (col >= 2 * EE);
#pragma unroll
        for (int mi = 0; mi < 4; ++mi) {
            int row = bn + wr * 64 + mi * 16 + lk * 4;
            if (isV) {
                int d   = col - 2 * EE;
                int bb2 = row >> 11;
                int tok = row & 2047;
                int c0  = (tok & ~31) | (lk << 3) | ((mi & 1) << 2);
                uint2 pk;
                pk.x = cvtpk(acc[mi][ni][0] + bv, acc[mi][ni][1] + bv);
                pk.y = cvtpk(acc[mi][ni][2] + bv, acc[mi][ni][3] + bv);
                *(uint2*)(vTp + ((size_t)(bb2 * HH + (d >> 6)) * DD + (d & 63)) * SS + c0) = pk;
            } else {
#pragma unroll
                for (int j = 0; j < 4; ++j) {
                    float vv = acc[mi][ni][j] + bv;
                    if (OUT_BF16 && col < EE) vv *= C2Q;
                    if (OUT_BF16)
                        ((ushort*)Cv)[(size_t)(row + j) * strideC + col] = f2bf(vv);
                    else
                        ((float*)Cv)[(size_t)(row + j) * strideC + col] = vv;
                }
            }
        }
    }
}

// ---------------- out-projection GEMM with fused combine ----------------
// A-operand = (po0 + po1) * (1/(l0+l1)) computed during reg-staging; B via
// global_load_lds (unchanged). LDS layout identical to gemm_mfma (linear dest,
// source-XOR gsh column), so the compute/epilogue body is byte-identical.
// h = k0>>6 is wave-uniform per K-step, so 1/lsum is 2 scalar pl loads per row.
__global__ __launch_bounds__(256) void gemm_out(const ushort* __restrict__ po,
                                                const float* __restrict__ pl,
                                                const ushort* __restrict__ Bw,
                                                const float* __restrict__ bias,
                                                float* __restrict__ C) {
    __shared__ ushort As[2][128 * 32];
    __shared__ ushort Bs[2][128 * 32];
    int id = blockIdx.y * gridDim.x + blockIdx.x;
    {
        int cpx = (gridDim.x * gridDim.y) >> 3;
        id = (id & 7) * cpx + (id >> 3);
    }
    const int bm = (id % gridDim.x) * 128;
    const int bn = (id / gridDim.x) * 128;
    const int K = EE;
    const int tid = threadIdx.x;
    const int w = tid >> 6, lane = tid & 63;
    const int l16 = lane & 15, lk = lane >> 4;
    const int wr = w >> 1, wc = w & 1;

    f32x4 acc[4][4];
#pragma unroll
    for (int mi = 0; mi < 4; mi++)
#pragma unroll
        for (int ni = 0; ni < 4; ni++)
            acc[mi][ni] = (f32x4){0.f, 0.f, 0.f, 0.f};

    const int ci  = w * 2;
    const int rA0 = lane >> 2;
    const int gsh = (lane & 3) ^ ((lane >> 2) & 3);

    const ushort* p0 = po;
    const ushort* p1 = po + (size_t)NR * EE;
    // per-thread fixed A rows and their (b, q) decode
    int rg[2], bq_b[2], bq_q[2];
#pragma unroll
    for (int i2 = 0; i2 < 2; ++i2) {
        rg[i2]   = bn + (ci + i2) * 16 + rA0;
        bq_b[i2] = rg[i2] >> 11;
        bq_q[i2] = rg[i2] & 2047;
    }

    short8 a0[2], a1[2];
    float  lv0[2], lv1[2];

#define ALOAD(k0)                                                                            \
    {                                                                                        \
        int h = (k0) >> 6;                                                                   \
        _Pragma("unroll") for (int i2 = 0; i2 < 2; ++i2) {                                   \
            const size_t off = (size_t)rg[i2] * EE + (k0) + gsh * 8;                         \
            a0[i2] = *(const short8*)(p0 + off);                                             \
            a1[i2] = *(const short8*)(p1 + off);                                             \
            lv0[i2] = pl[((size_t)(0 * BB + bq_b[i2]) * HH + h) * SS + bq_q[i2]];            \
            lv1[i2] = pl[((size_t)(1 * BB + bq_b[i2]) * HH + h) * SS + bq_q[i2]];            \
        }                                                                                    \
    }

#define AWRITE(buf)                                                                          \
    {                                                                                        \
        _Pragma("unroll") for (int i2 = 0; i2 < 2; ++i2) {                                   \
            float inv = 1.f / (lv0[i2] + lv1[i2]);                                           \
            uint4v u;                                                                        \
            _Pragma("unroll") for (int j = 0; j < 4; ++j) {                                  \
                float flo = (bf2f(a0[i2][2 * j])     + bf2f(a1[i2][2 * j]))     * inv;       \
                float fhi = (bf2f(a0[i2][2 * j + 1]) + bf2f(a1[i2][2 * j + 1])) * inv;       \
                u[j] = cvtpk(flo, fhi);                                                      \
            }                                                                                \
            *(uint4v*)&As[buf][(ci + i2) * 512 + lane * 8] = u;                              \
        }                                                                                    \
    }

#define BSTAGE(buf, k0)                                                                      \
    {                                                                                        \
        _Pragma("unroll") for (int i2 = 0; i2 < 2; ++i2) {                                   \
            int c = ci + i2;                                                                 \
            int r = c * 16 + rA0;                                                            \
            const ushort* gb = Bw + (size_t)(bm + r) * K + (k0) + gsh * 8;                   \
            __builtin_amdgcn_global_load_lds(                                                \
                (const __attribute__((address_space(1))) void*)gb,                           \
                (__attribute__((address_space(3))) void*)((char*)&Bs[buf][0] + c * 1024),    \
                16, 0, 0);                                                                   \
        }                                                                                    \
    }

    const int pp = (lk ^ (l16 & 3)) * 8;
    const int NT = K / 32;

    ALOAD(0);
    BSTAGE(0, 0);
    AWRITE(0);
    __syncthreads();

    for (int t = 0; t < NT; ++t) {
        int cur = t & 1;
        if (t + 1 < NT) { ALOAD((t + 1) * 32); BSTAGE(cur ^ 1, (t + 1) * 32); }
        const ushort* Ab = &As[cur][0];
        const ushort* Bb = &Bs[cur][0];
        short8 af[4], bfr[4];
#pragma unroll
        for (int mi = 0; mi < 4; ++mi) {
            int r = wr * 64 + mi * 16 + l16;
            af[mi] = *(const short8*)(Ab + r * 32 + pp);
        }
#pragma unroll
        for (int ni = 0; ni < 4; ++ni) {
            int r = wc * 64 + ni * 16 + l16;
            bfr[ni] = *(const short8*)(Bb + r * 32 + pp);
        }
#pragma unroll
        for (int mi = 0; mi < 4; ++mi)
#pragma unroll
            for (int ni = 0; ni < 4; ++ni)
                acc[mi][ni] = __builtin_amdgcn_mfma_f32_16x16x32_bf16(af[mi], bfr[ni], acc[mi][ni], 0, 0, 0);
        if (t + 1 < NT) AWRITE(cur ^ 1);
        __syncthreads();
    }
#undef ALOAD
#undef AWRITE
#undef BSTAGE

#pragma unroll
    for (int ni = 0; ni < 4; ++ni) {
        int col = bm + wc * 64 + ni * 16 + l16;
        float bv = bias[col];
#pragma unroll
        for (int mi = 0; mi < 4; ++mi) {
            int row = bn + wr * 64 + mi * 16 + lk * 4;
#pragma unroll
            for (int j = 0; j < 4; ++j)
                C[(size_t)(row + j) * EE + col] = acc[mi][ni][j] + bv;
        }
    }
}

// ---------------- attention (R16-proven body, unchanged) ----------------
__global__ __launch_bounds__(256, 2) void attn_mfma(const ushort* __restrict__ qk,
                                                    const ushort* __restrict__ vT,
                                                    const int* __restrict__ lbrk,
                                                    ushort* __restrict__ po,
                                                    float* __restrict__ pl) {
    __shared__ ushort ks[2][64 * 64];
    __shared__ ushort vt[2][64 * 64];

    int bid = (blockIdx.x & 7) * 128 + (blockIdx.x >> 3);
    const int kq = bid & 1;
    const int qb = (bid >> 1) & 15;
    const int h  = (bid >> 5) & 15;
    const int b  = bid >> 9;
    const int q0b = qb * QB;
    const int T0 = kq * 16;
    const int NTT = 16;
    const int tid = threadIdx.x;
    const int w = tid >> 6, lane = tid & 63;
    const int l16 = lane & 15, lk = lane >> 4;
    const int q0w = q0b + w * 32;

    const ushort* qk_b  = qk + (size_t)(b * SS) * QKW;
    const ushort* vT_bh = vT + ((size_t)(b * HH + h)) * DD * SS;

    short8 qf[2][2];
#pragma unroll
    for (int qg = 0; qg < 2; qg++)
#pragma unroll
        for (int kk = 0; kk < 2; kk++)
            qf[qg][kk] = *(const short8*)(qk_b + (size_t)(q0w + qg * 16 + l16) * QKW + h * DD + kk * 32 + lk * 8);

    int lb1[2]; uint wid[2];
#pragma unroll
    for (int qg = 0; qg < 2; qg++) {
        int q = q0w + qg * 16 + l16;
        int lb = lbrk[b * SS + q];
        lb1[qg] = lb + 1;
        wid[qg] = (uint)(q - lb);
    }

    const int srow = lane >> 3;
    const int slot = lane & 7;
    const ushort* gK[2];
    const ushort* gV[2];
#pragma unroll
    for (int i = 0; i < 2; i++) {
        int r = w * 16 + i * 8 + srow;
        int sl = (slot ^ (r & 7)) << 3;
        gK[i] = qk_b + (size_t)r * QKW + EE + h * DD + sl;
        gV[i] = vT_bh + (size_t)r * SS + sl;
    }

#define STAGE(buf, kt)                                                                            \
    {                                                                                             \
        _Pragma("unroll") for (int i = 0; i < 2; ++i) {                                           \
            __builtin_amdgcn_global_load_lds(                                                     \
                (const __attribute__((address_space(1))) void*)(gK[i] + (size_t)(kt) * 64 * QKW), \
                (__attribute__((address_space(3))) void*)((char*)&ks[buf][0] + w * 2048 + i * 1024), \
                16, 0, 0);                                                                        \
            __builtin_amdgcn_global_load_lds(                                                     \
                (const __attribute__((address_space(1))) void*)(gV[i] + (size_t)(kt) * 64),       \
                (__attribute__((address_space(3))) void*)((char*)&vt[buf][0] + w * 2048 + i * 1024), \
                16, 0, 0);                                                                        \
        }                                                                                         \
    }

    const int xr = l16 & 7;
    int perm[2];
#pragma unroll
    for (int u = 0; u < 2; u++) perm[u] = ((u * 4 + lk) ^ xr) << 3;

    short8 ones8;
#pragma unroll
    for (int i = 0; i < 8; i++) ones8[i] = (short)0x3F80;

    f32x4 o[4][2];
    f32x4 l_acc[2];
#pragma unroll
    for (int dg = 0; dg < 4; dg++)
#pragma unroll
        for (int qg = 0; qg < 2; qg++)
            o[dg][qg] = (f32x4){0.f, 0.f, 0.f, 0.f};
#pragma unroll
    for (int qg = 0; qg < 2; qg++) l_acc[qg] = (f32x4){0.f, 0.f, 0.f, 0.f};

    const int tmask = qb * 2 + 1;

    STAGE(0, T0);
    STAGE(1, T0 + 1);

    for (int t = 0; t < NTT; ++t) {
        if (t < NTT - 1) asm volatile("s_waitcnt vmcnt(4)" ::: "memory");
        else             asm volatile("s_waitcnt vmcnt(0)" ::: "memory");
        __builtin_amdgcn_s_barrier();

        const int T = T0 + t;
        const ushort* kb = &ks[t & 1][0];
        const ushort* vb = &vt[t & 1][0];
        const bool domask = (T <= tmask);

#pragma unroll
        for (int t32 = 0; t32 < 2; ++t32) {
            uint pu[2][4];
#pragma unroll
            for (int hi = 0; hi < 2; ++hi) {
                const int jg = t32 * 2 + hi;
                short8 kf0 = *(const short8*)(kb + (jg * 16 + l16) * 64 + perm[0]);
                short8 kf1 = *(const short8*)(kb + (jg * 16 + l16) * 64 + perm[1]);
                f32x4 s[2];
#pragma unroll
                for (int qg = 0; qg < 2; qg++) {
                    s[qg] = (f32x4){0.f, 0.f, 0.f, 0.f};
                    s[qg] = __builtin_amdgcn_mfma_f32_16x16x32_bf16(kf0, qf[qg][0], s[qg], 0, 0, 0);
                    s[qg] = __builtin_amdgcn_mfma_f32_16x16x32_bf16(kf1, qf[qg][1], s[qg], 0, 0, 0);
                }
                const int jbase = T * 64 + t32 * 32 + hi * 16 + lk * 4;
#pragma unroll
                for (int qg = 0; qg < 2; qg++) {
                    float p0, p1, p2, p3;
                    if (domask) {
                        int jb = jbase - lb1[qg];
                        p0 = vexp2((uint)(jb + 0) < wid[qg] ? -1e30f : s[qg][0]);
                        p1 = vexp2((uint)(jb + 1) < wid[qg] ? -1e30f : s[qg][1]);
                        p2 = vexp2((uint)(jb + 2) < wid[qg] ? -1e30f : s[qg][2]);
                        p3 = vexp2((uint)(jb + 3) < wid[qg] ? -1e30f : s[qg][3]);
                    } else {
                        p0 = vexp2(s[qg][0]);
                        p1 = vexp2(s[qg][1]);
                        p2 = vexp2(s[qg][2]);
                        p3 = vexp2(s[qg][3]);
                    }
                    pu[qg][hi * 2]     = cvtpk(p0, p1);
                    pu[qg][hi * 2 + 1] = cvtpk(p2, p3);
                }
            }
            short8 pfB[2];
#pragma unroll
            for (int qg = 0; qg < 2; qg++) {
                uint4v u;
                u[0] = pu[qg][0]; u[1] = pu[qg][1]; u[2] = pu[qg][2]; u[3] = pu[qg][3];
                pfB[qg] = __builtin_bit_cast(short8, u);
            }
#pragma unroll
            for (int qg = 0; qg < 2; qg++)
                l_acc[qg] = __builtin_amdgcn_mfma_f32_16x16x32_bf16(ones8, pfB[qg], l_acc[qg], 0, 0, 0);
#pragma unroll
            for (int dg = 0; dg < 4; dg++) {
                short8 vf = *(const short8*)(vb + (dg * 16 + l16) * 64 + perm[t32]);
#pragma unroll
                for (int qg = 0; qg < 2; qg++)
                    o[dg][qg] = __builtin_amdgcn_mfma_f32_16x16x32_bf16(vf, pfB[qg], o[dg][qg], 0, 0, 0);
            }
        }

        asm volatile("s_waitcnt lgkmcnt(0)" ::: "memory");
        __builtin_amdgcn_s_barrier();
        if (t + 2 < NTT) STAGE(t & 1, T0 + t + 2);
    }
#undef STAGE

    ushort* po_k = po + (size_t)kq * NR * EE;
#pragma unroll
    for (int qg = 0; qg < 2; qg++) {
        int qo = q0w + qg * 16 + l16;
        ushort* dst = po_k + (size_t)(b * SS + qo) * EE + h * DD + lk * 4;
#pragma unroll
        for (int dg = 0; dg < 4; dg++) {
            uint u0 = cvtpk(o[dg][qg][0], o[dg][qg][1]);
            uint u1 = cvtpk(o[dg][qg][2], o[dg][qg][3]);
            uint2 pk; pk.x = u0; pk.y = u1;
            *(uint2*)(dst + dg * 16) = pk;
        }
        if (lk == 0)
            pl[((size_t)(kq * BB + b) * HH + h) * SS + qo] = l_acc[qg][0];
    }
}

extern "C" void kernel_launch(void* const* d_in, const int* in_sizes, int n_in,
                              void* d_out, int out_size, void* d_ws, size_t ws_size,
                              hipStream_t stream) {
    const float* x    = (const float*)d_in[0];
    const int*   tok  = (const int*)d_in[1];
    const float* win  = (const float*)d_in[2];
    const float* bin  = (const float*)d_in[3];
    const float* wout = (const float*)d_in[4];
    const float* bout = (const float*)d_in[5];
    float* out = (float*)d_out;

    // ws layout (~53.6 MB total; proven in R12/R14/R16):
    //   xb | woutb | qkb | vTb | pl | lbrk | winb/po
    ushort* xb    = (ushort*)d_ws;                        // 4096*1024
    ushort* woutb = xb + (size_t)NR * EE;                 // 1024*1024
    ushort* qkb   = woutb + (size_t)EE * EE;              // 4096*2048
    ushort* vTb   = qkb + (size_t)NR * QKW;               // 2*16*64*2048
    float*  pl    = (float*)(vTb + (size_t)BB * HH * DD * SS);  // NSPLIT*2*16*2048 f32
    int*    lbrk  = (int*)(pl + (size_t)NSPLIT * BB * HH * SS); // 4096
    ushort* winb  = (ushort*)(lbrk + NR);                 // 3072*1024 (dead after gemm<1>)
    ushort* po    = winb;                                 // NSPLIT*4096*1024 (overlaps winb)

    int ncvt = (NR * EE + E3 * EE + EE * EE) / 8 / 256;   // 4096 cvt blocks
    cvt_scan<<<ncvt + BB, 256, 0, stream>>>(x, win, wout, xb, winb, woutb, tok, lbrk);

    gemm_mfma<1><<<dim3(E3 / 128, NR / 128), 256, 0, stream>>>(xb, winb, bin, (void*)qkb, vTb, QKW, EE);

    attn_mfma<<<BB * HH * (SS / QB) * NSPLIT, 256, 0, stream>>>(qkb, vTb, lbrk, po, pl);

    gemm_out<<<dim3(EE / 128, NR / 128), 256, 0, stream>>>(po, pl, woutb, bout, out);
}

// Round 18
// 125.628 us; speedup vs baseline: 1.0654x; 1.0654x over previous
//
#include <hip/hip_runtime.h>
#include <math.h>
#include <stdint.h>

#define BB 2
#define SS 2048
#define EE 1024
#define HH 16
#define DD 64
#define E3 3072
#define NR (BB*SS)   // 4096 rows
#define QKW 2048     // Q+K packed row width
#define NSPLIT 2     // attention K-split (R12-proven; 3 and 4 both regressed)
#define QB 128       // attention q-block rows (R16-proven: 4 blocks/CU, 60 VGPR)

// exp(s/8) = exp2(s * 0.18033688)
#define C2Q 0.18033688011112042f

typedef __attribute__((ext_vector_type(8))) short short8;   // 8 bf16
typedef __attribute__((ext_vector_type(4))) float f32x4;    // 4 fp32
typedef __attribute__((ext_vector_type(4))) uint uint4v;

__device__ __forceinline__ ushort f2bf(float f) {
    uint u = __float_as_uint(f);
    uint r = u + 0x7FFFu + ((u >> 16) & 1u);   // RNE
    return (ushort)(r >> 16);
}
__device__ __forceinline__ short8 pack8(float4 a, float4 b) {
    short8 v;
    v[0] = (short)f2bf(a.x); v[1] = (short)f2bf(a.y); v[2] = (short)f2bf(a.z); v[3] = (short)f2bf(a.w);
    v[4] = (short)f2bf(b.x); v[5] = (short)f2bf(b.y); v[6] = (short)f2bf(b.z); v[7] = (short)f2bf(b.w);
    return v;
}
__device__ __forceinline__ uint cvtpk(float lo, float hi) {
    uint d;
    asm("v_cvt_pk_bf16_f32 %0, %1, %2" : "=v"(d) : "v"(lo), "v"(hi));
    return d;
}
__device__ __forceinline__ float vexp2(float x) {
    float r;
    asm("v_exp_f32 %0, %1" : "=v"(r) : "v"(x));
    return r;
}

// ---------------- fp32->bf16 conversion + last-break scan, one launch ----------------
// (R17-proven correct.) Blocks [0, NCVT): convert x/win/wout. Blocks [NCVT, NCVT+BB): scan.
__global__ __launch_bounds__(256) void cvt_scan(const float* __restrict__ x,
                                                const float* __restrict__ win,
                                                const float* __restrict__ wout,
                                                ushort* __restrict__ xb,
                                                ushort* __restrict__ winb,
                                                ushort* __restrict__ woutb,
                                                const int* __restrict__ tok,
                                                int* __restrict__ lbrk) {
    const int NX = NR * EE / 8, NW = E3 * EE / 8, NWO = EE * EE / 8;
    const int NCVT = (NX + NW + NWO) / 256;
    __shared__ int pmax[256];
    int blk = blockIdx.x;
    int t = threadIdx.x;
    if (blk >= NCVT) {
        int b = blk - NCVT;
        int loc[8];
        int base = b * SS + t * 8;
        int lm = -1;
#pragma unroll
        for (int i = 0; i < 8; i++) {
            if (tok[base + i] == 13) lm = t * 8 + i;
            loc[i] = lm;
        }
        pmax[t] = lm;
        __syncthreads();
        if (t == 0) {
            int acc = -1;
            for (int i = 0; i < 256; i++) { int tmp = pmax[i]; pmax[i] = acc; acc = max(acc, tmp); }
        }
        __syncthreads();
        int off = pmax[t];
#pragma unroll
        for (int i = 0; i < 8; i++)
            lbrk[base + i] = max(off, loc[i]);
        return;
    }
    int i = blk * 256 + t;
    const float* src; ushort* dst; int j;
    if (i < NX)           { src = x;    dst = xb;    j = i; }
    else if (i < NX + NW) { src = win;  dst = winb;  j = i - NX; }
    else                  { src = wout; dst = woutb; j = i - NX - NW; }
    const float4* p = (const float4*)src + (size_t)j * 2;
    float4 a = p[0], b = p[1];
    *((short8*)dst + j) = pack8(a, b);
}

// ---------------- bf16 MFMA GEMM (R14/R16-proven, unchanged) ----------------
template<int OUT_BF16>
__global__ __launch_bounds__(256) void gemm_mfma(const ushort* __restrict__ A,
                                                 const ushort* __restrict__ Bw,
                                                 const float* __restrict__ bias,
                                                 void* __restrict__ Cv,
                                                 ushort* __restrict__ vTp,
                                                 int strideC, int K) {
    __shared__ ushort As[2][128 * 32];
    __shared__ ushort Bs[2][128 * 32];
    int id = blockIdx.y * gridDim.x + blockIdx.x;
    {
        int cpx = (gridDim.x * gridDim.y) >> 3;
        id = (id & 7) * cpx + (id >> 3);
    }
    const int bm = (id % gridDim.x) * 128;
    const int bn = (id / gridDim.x) * 128;
    const int tid = threadIdx.x;
    const int w = tid >> 6, lane = tid & 63;
    const int l16 = lane & 15, lk = lane >> 4;
    const int wr = w >> 1, wc = w & 1;

    f32x4 acc[4][4];
#pragma unroll
    for (int mi = 0; mi < 4; mi++)
#pragma unroll
        for (int ni = 0; ni < 4; ni++)
            acc[mi][ni] = (f32x4){0.f, 0.f, 0.f, 0.f};

    const int ci  = w * 2;
    const int rA0 = lane >> 2;
    const int gsh = (lane & 3) ^ ((lane >> 2) & 3);

#define GSTAGE(buf, k0)                                                                      \
    {                                                                                        \
        _Pragma("unroll") for (int i2 = 0; i2 < 2; ++i2) {                                   \
            int c = ci + i2;                                                                 \
            int r = c * 16 + rA0;                                                            \
            const ushort* ga = A + (size_t)(bn + r) * K + (k0) + gsh * 8;                    \
            const ushort* gb = Bw + (size_t)(bm + r) * K + (k0) + gsh * 8;                   \
            __builtin_amdgcn_global_load_lds(                                                \
                (const __attribute__((address_space(1))) void*)ga,                           \
                (__attribute__((address_space(3))) void*)((char*)&As[buf][0] + c * 1024),    \
                16, 0, 0);                                                                   \
            __builtin_amdgcn_global_load_lds(                                                \
                (const __attribute__((address_space(1))) void*)gb,                           \
                (__attribute__((address_space(3))) void*)((char*)&Bs[buf][0] + c * 1024),    \
                16, 0, 0);                                                                   \
        }                                                                                    \
    }

    const int pp = (lk ^ (l16 & 3)) * 8;
    const int NT = K / 32;

    GSTAGE(0, 0);
    __syncthreads();

    for (int t = 0; t < NT; ++t) {
        int cur = t & 1;
        if (t + 1 < NT) GSTAGE(cur ^ 1, (t + 1) * 32);
        const ushort* Ab = &As[cur][0];
        const ushort* Bb = &Bs[cur][0];
        short8 af[4], bfr[4];
#pragma unroll
        for (int mi = 0; mi < 4; ++mi) {
            int r = wr * 64 + mi * 16 + l16;
            af[mi] = *(const short8*)(Ab + r * 32 + pp);
        }
#pragma unroll
        for (int ni = 0; ni < 4; ++ni) {
            int r = wc * 64 + ni * 16 + l16;
            bfr[ni] = *(const short8*)(Bb + r * 32 + pp);
        }
#pragma unroll
        for (int mi = 0; mi < 4; ++mi)
#pragma unroll
            for (int ni = 0; ni < 4; ++ni)
                acc[mi][ni] = __builtin_amdgcn_mfma_f32_16x16x32_bf16(af[mi], bfr[ni], acc[mi][ni], 0, 0, 0);
        __syncthreads();
    }
#undef GSTAGE

#pragma unroll
    for (int ni = 0; ni < 4; ++ni) {
        int col = bm + wc * 64 + ni * 16 + l16;
        float bv = bias[col];
        const bool isV = OUT_BF16 && (col >= 2 * EE);
#pragma unroll
        for (int mi = 0; mi < 4; ++mi) {
            int row = bn + wr * 64 + mi * 16 + lk * 4;
            if (isV) {
                int d   = col - 2 * EE;
                int bb2 = row >> 11;
                int tok = row & 2047;
                int c0  = (tok & ~31) | (lk << 3) | ((mi & 1) << 2);
                uint2 pk;
                pk.x = cvtpk(acc[mi][ni][0] + bv, acc[mi][ni][1] + bv);
                pk.y = cvtpk(acc[mi][ni][2] + bv, acc[mi][ni][3] + bv);
                *(uint2*)(vTp + ((size_t)(bb2 * HH + (d >> 6)) * DD + (d & 63)) * SS + c0) = pk;
            } else {
#pragma unroll
                for (int j = 0; j < 4; ++j) {
                    float vv = acc[mi][ni][j] + bv;
                    if (OUT_BF16 && col < EE) vv *= C2Q;
                    if (OUT_BF16)
                        ((ushort*)Cv)[(size_t)(row + j) * strideC + col] = f2bf(vv);
                    else
                        ((float*)Cv)[(size_t)(row + j) * strideC + col] = vv;
                }
            }
        }
    }
}

// ---------------- attention (R16-proven body, unchanged) ----------------
__global__ __launch_bounds__(256, 2) void attn_mfma(const ushort* __restrict__ qk,
                                                    const ushort* __restrict__ vT,
                                                    const int* __restrict__ lbrk,
                                                    ushort* __restrict__ po,
                                                    float* __restrict__ pl) {
    __shared__ ushort ks[2][64 * 64];
    __shared__ ushort vt[2][64 * 64];

    int bid = (blockIdx.x & 7) * 128 + (blockIdx.x >> 3);
    const int kq = bid & 1;
    const int qb = (bid >> 1) & 15;
    const int h  = (bid >> 5) & 15;
    const int b  = bid >> 9;
    const int q0b = qb * QB;
    const int T0 = kq * 16;
    const int NTT = 16;
    const int tid = threadIdx.x;
    const int w = tid >> 6, lane = tid & 63;
    const int l16 = lane & 15, lk = lane >> 4;
    const int q0w = q0b + w * 32;

    const ushort* qk_b  = qk + (size_t)(b * SS) * QKW;
    const ushort* vT_bh = vT + ((size_t)(b * HH + h)) * DD * SS;

    short8 qf[2][2];
#pragma unroll
    for (int qg = 0; qg < 2; qg++)
#pragma unroll
        for (int kk = 0; kk < 2; kk++)
            qf[qg][kk] = *(const short8*)(qk_b + (size_t)(q0w + qg * 16 + l16) * QKW + h * DD + kk * 32 + lk * 8);

    int lb1[2]; uint wid[2];
#pragma unroll
    for (int qg = 0; qg < 2; qg++) {
        int q = q0w + qg * 16 + l16;
        int lb = lbrk[b * SS + q];
        lb1[qg] = lb + 1;
        wid[qg] = (uint)(q - lb);
    }

    const int srow = lane >> 3;
    const int slot = lane & 7;
    const ushort* gK[2];
    const ushort* gV[2];
#pragma unroll
    for (int i = 0; i < 2; i++) {
        int r = w * 16 + i * 8 + srow;
        int sl = (slot ^ (r & 7)) << 3;
        gK[i] = qk_b + (size_t)r * QKW + EE + h * DD + sl;
        gV[i] = vT_bh + (size_t)r * SS + sl;
    }

#define STAGE(buf, kt)                                                                            \
    {                                                                                             \
        _Pragma("unroll") for (int i = 0; i < 2; ++i) {                                           \
            __builtin_amdgcn_global_load_lds(                                                     \
                (const __attribute__((address_space(1))) void*)(gK[i] + (size_t)(kt) * 64 * QKW), \
                (__attribute__((address_space(3))) void*)((char*)&ks[buf][0] + w * 2048 + i * 1024), \
                16, 0, 0);                                                                        \
            __builtin_amdgcn_global_load_lds(                                                     \
                (const __attribute__((address_space(1))) void*)(gV[i] + (size_t)(kt) * 64),       \
                (__attribute__((address_space(3))) void*)((char*)&vt[buf][0] + w * 2048 + i * 1024), \
                16, 0, 0);                                                                        \
        }                                                                                         \
    }

    const int xr = l16 & 7;
    int perm[2];
#pragma unroll
    for (int u = 0; u < 2; u++) perm[u] = ((u * 4 + lk) ^ xr) << 3;

    short8 ones8;
#pragma unroll
    for (int i = 0; i < 8; i++) ones8[i] = (short)0x3F80;

    f32x4 o[4][2];
    f32x4 l_acc[2];
#pragma unroll
    for (int dg = 0; dg < 4; dg++)
#pragma unroll
        for (int qg = 0; qg < 2; qg++)
            o[dg][qg] = (f32x4){0.f, 0.f, 0.f, 0.f};
#pragma unroll
    for (int qg = 0; qg < 2; qg++) l_acc[qg] = (f32x4){0.f, 0.f, 0.f, 0.f};

    const int tmask = qb * 2 + 1;

    STAGE(0, T0);
    STAGE(1, T0 + 1);

    for (int t = 0; t < NTT; ++t) {
        if (t < NTT - 1) asm volatile("s_waitcnt vmcnt(4)" ::: "memory");
        else             asm volatile("s_waitcnt vmcnt(0)" ::: "memory");
        __builtin_amdgcn_s_barrier();

        const int T = T0 + t;
        const ushort* kb = &ks[t & 1][0];
        const ushort* vb = &vt[t & 1][0];
        const bool domask = (T <= tmask);

#pragma unroll
        for (int t32 = 0; t32 < 2; ++t32) {
            uint pu[2][4];
#pragma unroll
            for (int hi = 0; hi < 2; ++hi) {
                const int jg = t32 * 2 + hi;
                short8 kf0 = *(const short8*)(kb + (jg * 16 + l16) * 64 + perm[0]);
                short8 kf1 = *(const short8*)(kb + (jg * 16 + l16) * 64 + perm[1]);
                f32x4 s[2];
#pragma unroll
                for (int qg = 0; qg < 2; qg++) {
                    s[qg] = (f32x4){0.f, 0.f, 0.f, 0.f};
                    s[qg] = __builtin_amdgcn_mfma_f32_16x16x32_bf16(kf0, qf[qg][0], s[qg], 0, 0, 0);
                    s[qg] = __builtin_amdgcn_mfma_f32_16x16x32_bf16(kf1, qf[qg][1], s[qg], 0, 0, 0);
                }
                const int jbase = T * 64 + t32 * 32 + hi * 16 + lk * 4;
#pragma unroll
                for (int qg = 0; qg < 2; qg++) {
                    float p0, p1, p2, p3;
                    if (domask) {
                        int jb = jbase - lb1[qg];
                        p0 = vexp2((uint)(jb + 0) < wid[qg] ? -1e30f : s[qg][0]);
                        p1 = vexp2((uint)(jb + 1) < wid[qg] ? -1e30f : s[qg][1]);
                        p2 = vexp2((uint)(jb + 2) < wid[qg] ? -1e30f : s[qg][2]);
                        p3 = vexp2((uint)(jb + 3) < wid[qg] ? -1e30f : s[qg][3]);
                    } else {
                        p0 = vexp2(s[qg][0]);
                        p1 = vexp2(s[qg][1]);
                        p2 = vexp2(s[qg][2]);
                        p3 = vexp2(s[qg][3]);
                    }
                    pu[qg][hi * 2]     = cvtpk(p0, p1);
                    pu[qg][hi * 2 + 1] = cvtpk(p2, p3);
                }
            }
            short8 pfB[2];
#pragma unroll
            for (int qg = 0; qg < 2; qg++) {
                uint4v u;
                u[0] = pu[qg][0]; u[1] = pu[qg][1]; u[2] = pu[qg][2]; u[3] = pu[qg][3];
                pfB[qg] = __builtin_bit_cast(short8, u);
            }
#pragma unroll
            for (int qg = 0; qg < 2; qg++)
                l_acc[qg] = __builtin_amdgcn_mfma_f32_16x16x32_bf16(ones8, pfB[qg], l_acc[qg], 0, 0, 0);
#pragma unroll
            for (int dg = 0; dg < 4; dg++) {
                short8 vf = *(const short8*)(vb + (dg * 16 + l16) * 64 + perm[t32]);
#pragma unroll
                for (int qg = 0; qg < 2; qg++)
                    o[dg][qg] = __builtin_amdgcn_mfma_f32_16x16x32_bf16(vf, pfB[qg], o[dg][qg], 0, 0, 0);
            }
        }

        asm volatile("s_waitcnt lgkmcnt(0)" ::: "memory");
        __builtin_amdgcn_s_barrier();
        if (t + 2 < NTT) STAGE(t & 1, T0 + t + 2);
    }
#undef STAGE

    ushort* po_k = po + (size_t)kq * NR * EE;
#pragma unroll
    for (int qg = 0; qg < 2; qg++) {
        int qo = q0w + qg * 16 + l16;
        ushort* dst = po_k + (size_t)(b * SS + qo) * EE + h * DD + lk * 4;
#pragma unroll
        for (int dg = 0; dg < 4; dg++) {
            uint u0 = cvtpk(o[dg][qg][0], o[dg][qg][1]);
            uint u1 = cvtpk(o[dg][qg][2], o[dg][qg][3]);
            uint2 pk; pk.x = u0; pk.y = u1;
            *(uint2*)(dst + dg * 16) = pk;
        }
        if (lk == 0)
            pl[((size_t)(kq * BB + b) * HH + h) * SS + qo] = l_acc[qg][0];
    }
}

// ---------------- combine: aob = sum_k po_k / sum_k l_k, bf16 (R16-proven) ----------------
__global__ __launch_bounds__(256) void combine(const ushort* __restrict__ po,
                                               const float* __restrict__ pl,
                                               ushort* __restrict__ aob) {
    int i8 = blockIdx.x * 256 + threadIdx.x;      // 0 .. NR*EE/8-1
    const int bq = i8 >> 7;                        // b*SS + q
    const int h  = (i8 >> 3) & 15;
    const int b  = bq >> 11;
    const int q  = bq & 2047;
    float lsum = 0.f;
#pragma unroll
    for (int k = 0; k < NSPLIT; k++)
        lsum += pl[((size_t)(k * BB + b) * HH + h) * SS + q];
    float inv = 1.f / lsum;
    float accv[8] = {0.f};
#pragma unroll
    for (int k = 0; k < NSPLIT; k++) {
        short8 a = *((const short8*)(po + (size_t)k * NR * EE) + i8);
#pragma unroll
        for (int j = 0; j < 8; j++)
            accv[j] += __uint_as_float(((uint)(ushort)a[j]) << 16);
    }
    short8 r;
#pragma unroll
    for (int j = 0; j < 8; j++)
        r[j] = (short)f2bf(accv[j] * inv);
    *((short8*)aob + i8) = r;
}

extern "C" void kernel_launch(void* const* d_in, const int* in_sizes, int n_in,
                              void* d_out, int out_size, void* d_ws, size_t ws_size,
                              hipStream_t stream) {
    const float* x    = (const float*)d_in[0];
    const int*   tok  = (const int*)d_in[1];
    const float* win  = (const float*)d_in[2];
    const float* bin  = (const float*)d_in[3];
    const float* wout = (const float*)d_in[4];
    const float* bout = (const float*)d_in[5];
    float* out = (float*)d_out;

    // ws layout (~53.6 MB total; proven in R12/R14/R16):
    //   xb (reused as aob after QKV GEMM) | woutb | qkb | vTb | pl | lbrk | winb/po
    ushort* xb    = (ushort*)d_ws;                        // 4096*1024      (also aob)
    ushort* woutb = xb + (size_t)NR * EE;                 // 1024*1024
    ushort* qkb   = woutb + (size_t)EE * EE;              // 4096*2048
    ushort* vTb   = qkb + (size_t)NR * QKW;               // 2*16*64*2048
    float*  pl    = (float*)(vTb + (size_t)BB * HH * DD * SS);  // NSPLIT*2*16*2048 f32
    int*    lbrk  = (int*)(pl + (size_t)NSPLIT * BB * HH * SS); // 4096
    ushort* winb  = (ushort*)(lbrk + NR);                 // 3072*1024 (dead after gemm<1>)
    ushort* po    = winb;                                 // NSPLIT*4096*1024 (overlaps winb)
    ushort* aob   = xb;                                   // alias (xb dead after gemm<1>)

    int ncvt = (NR * EE + E3 * EE + EE * EE) / 8 / 256;   // 4096 cvt blocks
    cvt_scan<<<ncvt + BB, 256, 0, stream>>>(x, win, wout, xb, winb, woutb, tok, lbrk);

    gemm_mfma<1><<<dim3(E3 / 128, NR / 128), 256, 0, stream>>>(xb, winb, bin, (void*)qkb, vTb, QKW, EE);

    attn_mfma<<<BB * HH * (SS / QB) * NSPLIT, 256, 0, stream>>>(qkb, vTb, lbrk, po, pl);

    combine<<<NR * EE / 8 / 256, 256, 0, stream>>>(po, pl, aob);

    gemm_mfma<0><<<dim3(EE / 128, NR / 128), 256, 0, stream>>>(aob, woutb, bout, (void*)out, nullptr, EE, EE);
}